// Round 13
// baseline (127.530 us; speedup 1.0000x reference)
//
#include <hip/hip_runtime.h>
#include <hip/hip_bf16.h>
#include <stdint.h>
#include <math.h>

typedef __bf16 bf16x8 __attribute__((ext_vector_type(8)));
typedef float  f32x4  __attribute__((ext_vector_type(4)));

#define NROWS   8192
#define DIMK    128
#define NGROUPS 2048
#define RECON_N 6422528
#define SIM_BLOCKS   2080            // upper-triangle 128x128 tile pairs (64*65/2)
#define RECON_BLOCKS 1568
#define GROUP_BLOCKS 512
#define FUSED_BLOCKS 4160            // 512 supergroups of 8 (4s,3r,1g) + 64 tail

// workspace layout (float offsets)
#define WS_S      0                  // S[8192] atomic accum (zeroed by prep)
#define WS_G      8192
#define WS_E      16384
#define WS_RPART  24576              // 1568
#define WS_DPART  26144              // 512
#define WS_PB     26656              // byte 106624 (16B aligned); bf16 P, 2MB

__device__ __forceinline__ void async16(const void* g, void* l) {
    __builtin_amdgcn_global_load_lds(
        (const __attribute__((address_space(1))) void*)g,
        (__attribute__((address_space(3))) void*)l, 16, 0, 0);
}

__device__ __forceinline__ unsigned short f2bf(float f) {
    union { __hip_bfloat16 h; unsigned short u; } v;
    v.h = __float2bfloat16(f);
    return v.u;
}

// -------- k1: convert P fp32->bf16 + zero S --------
__global__ __launch_bounds__(256) void prep_kernel(const float4* __restrict__ Pf,
                                                   uint2* __restrict__ Pb,
                                                   float* __restrict__ ws) {
    int bx = blockIdx.x;
    if (bx < 1024) {
        int idx = bx * 256 + threadIdx.x;        // 262144 float4s
        float4 a = Pf[idx];
        uint2 r;
        r.x = (uint32_t)f2bf(a.x) | ((uint32_t)f2bf(a.y) << 16);
        r.y = (uint32_t)f2bf(a.z) | ((uint32_t)f2bf(a.w) << 16);
        Pb[idx] = r;
    } else {
        int zb = bx - 1024;                      // 8 blocks zero S
        ((float4*)(ws + WS_S))[zb * 256 + threadIdx.x] = (float4){0.f, 0.f, 0.f, 0.f};
    }
}

// -------- k2: fused = triangle-sim + recon + group --------
__global__ __launch_bounds__(256, 4) void fused_kernel(
        const unsigned short* __restrict__ Pb,
        const float* __restrict__ Pf,
        const float4* __restrict__ X,
        const float4* __restrict__ Y,
        float* __restrict__ ws) {
    __shared__ unsigned short tile[64 * 128];    // 16 KB (sim B staging)
    __shared__ float red[4];
    const int bx = blockIdx.x;
    const int wave = threadIdx.x >> 6, lane = threadIdx.x & 63;

    int role, idx;                               // 0=sim 1=recon 2=group
    if (bx < 4096) {
        int g = bx >> 3, r8 = bx & 7;
        if (r8 < 4)      { role = 0; idx = g * 4 + r8; }
        else if (r8 < 7) { role = 1; idx = g * 3 + (r8 - 4); }
        else             { role = 2; idx = g; }
    } else if (bx < 4128) {
        role = 0; idx = 2048 + (bx - 4096);
    } else {
        role = 1; idx = 1536 + (bx - 4128);
    }

    if (role == 0) {
        // ---- triangle sim: tile pair (I,J), I<=J, 128x128 ----
        float* S = ws + WS_S;
        // decode (I,J) from linear idx: rowStart(I) = 64I - I(I-1)/2
        int I = (int)(64.5f - sqrtf(64.5f * 64.5f - 2.0f * (float)idx));
        int rs = 64 * I - (I * (I - 1)) / 2;
        while (rs > idx) { --I; rs = 64 * I - (I * (I - 1)) / 2; }
        while (64 * (I + 1) - ((I + 1) * I) / 2 <= idx) { ++I; }
        rs = 64 * I - (I * (I - 1)) / 2;
        const int J = I + (idx - rs);
        const int rowBase = I * 128, colBase = J * 128;
        const int m = lane & 15, kq = lane >> 4;

        // A fragments from global (L2-hot): rows rowBase + wave*32 + i*16 + m
        bf16x8 Af[2][4];
#pragma unroll
        for (int i = 0; i < 2; ++i) {
            const unsigned short* rowp =
                Pb + (size_t)(rowBase + wave * 32 + i * 16 + m) * DIMK + kq * 8;
#pragma unroll
            for (int kk = 0; kk < 4; ++kk)
                Af[i][kk] = *(const bf16x8*)(rowp + kk * 32);
        }

        // swizzled staging source offsets: phys chunk (rp,qp) <- logical (rp,(qp-rp)&15)
        int srcOff[4];
#pragma unroll
        for (int ii = 0; ii < 4; ++ii) {
            int chunk = (ii * 4 + wave) * 64 + lane;
            int r = chunk >> 4, qp = chunk & 15;
            srcOff[ii] = r * 256 + (((qp - r) & 15) << 4);
        }

        float rowAcc[2][4], colAcc[2][4];
#pragma unroll
        for (int i = 0; i < 2; ++i)
#pragma unroll
            for (int r = 0; r < 4; ++r) { rowAcc[i][r] = 0.f; colAcc[i][r] = 0.f; }

        for (int t = 0; t < 2; ++t) {
            if (t) __syncthreads();              // readers of t=0 done
            {
                const char* g = (const char*)(Pb + (size_t)(colBase + t * 64) * DIMK);
#pragma unroll
                for (int ii = 0; ii < 4; ++ii) {
                    int seg = ii * 4 + wave;
                    async16(g + srcOff[ii], (char*)tile + seg * 1024 + lane * 16);
                }
            }
            __syncthreads();

#pragma unroll
            for (int j = 0; j < 4; ++j) {
                int rl = j * 16 + m;
                bf16x8 Bf[4];
#pragma unroll
                for (int kk = 0; kk < 4; ++kk)
                    Bf[kk] = *(const bf16x8*)((const char*)tile + rl * 256 +
                                              (((kq + kk * 4 + rl) & 15) << 4));
                f32x4 acc[2];
#pragma unroll
                for (int i = 0; i < 2; ++i) acc[i] = (f32x4){0.f, 0.f, 0.f, 0.f};
#pragma unroll
                for (int kk = 0; kk < 4; ++kk)
#pragma unroll
                    for (int i = 0; i < 2; ++i)
                        acc[i] = __builtin_amdgcn_mfma_f32_16x16x32_bf16(
                            Af[i][kk], Bf[kk], acc[i], 0, 0, 0);
#pragma unroll
                for (int i = 0; i < 2; ++i)
#pragma unroll
                    for (int r = 0; r < 4; ++r) {
                        float e = __expf(acc[i][r] * 10.0f);
                        rowAcc[i][r] += e;       // row sums (over this tile's cols)
                        colAcc[t][j] += e;       // col sums (over this tile's rows)
                    }
            }
        }

        // row sums: reduce the 16 lanes sharing a row (low 4 lane bits)
#pragma unroll
        for (int i = 0; i < 2; ++i)
#pragma unroll
            for (int r = 0; r < 4; ++r) {
                float sv = rowAcc[i][r];
                sv += __shfl_xor(sv, 1, 64);
                sv += __shfl_xor(sv, 2, 64);
                sv += __shfl_xor(sv, 4, 64);
                sv += __shfl_xor(sv, 8, 64);
                if ((lane & 15) == 0)
                    atomicAdd(&S[rowBase + wave * 32 + i * 16 + (lane >> 4) * 4 + r], sv);
            }
        // col sums: reduce the 4 row-quads (high 2 lane bits); skip on diagonal
        if (I != J) {
#pragma unroll
            for (int t = 0; t < 2; ++t)
#pragma unroll
                for (int j = 0; j < 4; ++j) {
                    float cv = colAcc[t][j];
                    cv += __shfl_xor(cv, 16, 64);
                    cv += __shfl_xor(cv, 32, 64);
                    if (lane < 16)
                        atomicAdd(&S[colBase + t * 64 + j * 16 + lane], cv);
                }
        }
    } else if (role == 1) {
        // ---------------- recon ----------------
        int base = idx * 1024 + threadIdx.x;
        float4 a0 = X[base],       b0 = Y[base];
        float4 a1 = X[base + 256], b1 = Y[base + 256];
        float4 a2 = X[base + 512], b2 = Y[base + 512];
        float4 a3 = X[base + 768], b3 = Y[base + 768];
        float s = 0.f, d;
        d = a0.x - b0.x; s += d * d;  d = a0.y - b0.y; s += d * d;
        d = a0.z - b0.z; s += d * d;  d = a0.w - b0.w; s += d * d;
        d = a1.x - b1.x; s += d * d;  d = a1.y - b1.y; s += d * d;
        d = a1.z - b1.z; s += d * d;  d = a1.w - b1.w; s += d * d;
        d = a2.x - b2.x; s += d * d;  d = a2.y - b2.y; s += d * d;
        d = a2.z - b2.z; s += d * d;  d = a2.w - b2.w; s += d * d;
        d = a3.x - b3.x; s += d * d;  d = a3.y - b3.y; s += d * d;
        d = a3.z - b3.z; s += d * d;  d = a3.w - b3.w; s += d * d;
#pragma unroll
        for (int mm = 1; mm < 64; mm <<= 1) s += __shfl_xor(s, mm, 64);
        if (lane == 0) red[wave] = s;
        __syncthreads();
        if (threadIdx.x == 0)
            ws[WS_RPART + idx] = red[0] + red[1] + red[2] + red[3];
    } else {
        // ---------------- group ----------------
        float* G = ws + WS_G;
        float* E = ws + WS_E;
        int g = idx * 4 + wave;
        const float* base = Pf + (size_t)g * 4 * DIMK;
        float v[4][2];
#pragma unroll
        for (int r = 0; r < 4; ++r) {
            v[r][0] = base[r * DIMK + lane];
            v[r][1] = base[r * DIMK + 64 + lane];
        }
        float dmat[4][4];
#pragma unroll
        for (int r = 0; r < 4; ++r)
#pragma unroll
            for (int s2 = r; s2 < 4; ++s2) {
                float p = v[r][0] * v[s2][0] + v[r][1] * v[s2][1];
#pragma unroll
                for (int mm = 1; mm < 64; mm <<= 1) p += __shfl_xor(p, mm, 64);
                dmat[r][s2] = p; dmat[s2][r] = p;
            }
        if (lane == 0) {
            float distp = 0.f;
#pragma unroll
            for (int r = 0; r < 4; ++r)
#pragma unroll
                for (int s2 = r + 1; s2 < 4; ++s2)
                    distp += dmat[r][r] + dmat[s2][s2] - 2.f * dmat[r][s2];
            red[wave] = distp;
#pragma unroll
            for (int r = 0; r < 4; ++r) {
                float Gs = 0.f, Es = 0.f;
#pragma unroll
                for (int s2 = 0; s2 < 4; ++s2) {
                    float sim = dmat[r][s2] * 10.0f;
                    float e = __expf(sim);
                    Gs += e;
                    if (sim == 1.0f) Es += e;
                }
                G[g * 4 + r] = Gs;
                E[g * 4 + r] = Es;
            }
        }
        __syncthreads();
        if (threadIdx.x == 0)
            ws[WS_DPART + idx] = red[0] + red[1] + red[2] + red[3];
    }
}

// -------- k3: finalize — one 1024-thread block --------
__global__ __launch_bounds__(1024) void finalize_kernel(const float* __restrict__ ws,
                                                        float* __restrict__ out) {
    __shared__ float redc[16], redr[16], redd[16];
    const float* S = ws + WS_S;
    const float* G = ws + WS_G;
    const float* E = ws + WS_E;

    float c = 0.f;
    for (int r = threadIdx.x; r < NROWS; r += 1024)
        c += __logf(S[r] - E[r]) - __logf(G[r] - E[r]);
    float rs = 0.f;
    for (int i = threadIdx.x; i < RECON_BLOCKS; i += 1024) rs += ws[WS_RPART + i];
    float ds = 0.f;
    for (int i = threadIdx.x; i < GROUP_BLOCKS; i += 1024) ds += ws[WS_DPART + i];

#pragma unroll
    for (int mm = 1; mm < 64; mm <<= 1) {
        c  += __shfl_xor(c,  mm, 64);
        rs += __shfl_xor(rs, mm, 64);
        ds += __shfl_xor(ds, mm, 64);
    }
    int wave = threadIdx.x >> 6, lane = threadIdx.x & 63;
    if (lane == 0) { redc[wave] = c; redr[wave] = rs; redd[wave] = ds; }
    __syncthreads();
    if (threadIdx.x == 0) {
        float cs = 0.f, rss = 0.f, dss = 0.f;
#pragma unroll
        for (int i = 0; i < 16; ++i) { cs += redc[i]; rss += redr[i]; dss += redd[i]; }
        float closs = cs / (float)NROWS;
        float recon = rss / (float)RECON_N;
        float dist  = dss / (float)(NGROUPS * 6 * DIMK);
        out[0] = recon + closs + dist;
        out[1] = closs;
        out[2] = recon;
        out[3] = dist;
    }
}

extern "C" void kernel_launch(void* const* d_in, const int* in_sizes, int n_in,
                              void* d_out, int out_size, void* d_ws, size_t ws_size,
                              hipStream_t stream) {
    const float* P  = (const float*)d_in[0];    // projections 8192x128 fp32
    const float4* X = (const float4*)d_in[1];   // xrecon 8192x784 fp32
    const float4* Y = (const float4*)d_in[2];   // recon_label fp32
    float* out = (float*)d_out;                 // 4 fp32 scalars
    float* w = (float*)d_ws;
    unsigned short* Pb = (unsigned short*)(w + WS_PB);

    prep_kernel<<<1032, 256, 0, stream>>>((const float4*)P, (uint2*)Pb, w);
    fused_kernel<<<FUSED_BLOCKS, 256, 0, stream>>>(Pb, P, X, Y, w);
    finalize_kernel<<<1, 1024, 0, stream>>>(w, out);
}